// Round 9
// baseline (356.056 us; speedup 1.0000x reference)
//
#include <hip/hip_runtime.h>
#include <hip/hip_cooperative_groups.h>
#include <math.h>

namespace cg = cooperative_groups;

#define KM 16
#define KS 64
#define TWO_PI_F 6.283185307179586477f

// Workspace float-offset layout:
//   [0..64]      sxk (65) spline x knots      [65..129]  syk (65)
//   [130..194]   sdk (65)                     [195..258] sknot (64) sorted outer knots
//   [8709..12868]  SROOT: 65 intervals * 64 sorted sub-roots
//   [12872..418471] COEF: 4225 regions * 96 floats (48 (a,b) pairs):
//                   theta_o(r) = a_o*r + b_o inside region (v,s)
#define WS_SXK   0
#define WS_SYK   65
#define WS_SDK   130
#define WS_KNOT  195
#define WS_SROOT 8709
#define WS_COEF  12872
#define WS_NEED  (12872 + 4225 * 96)   // floats

__device__ __forceinline__ float frcp(float x) { return __builtin_amdgcn_rcpf(x); }

// 4-quadrant atan2, max err ~1e-5 rad (tolerance 3.1e-2).
__device__ __forceinline__ float fast_atan2(float y, float x) {
    const float ax = fabsf(x), ay = fabsf(y);
    const float mx = fmaxf(ax, ay), mn = fminf(ax, ay);
    const float t = mn * frcp(mx);
    const float s = t * t;
    float p = -0.01172120f;
    p = fmaf(p, s,  0.05265332f);
    p = fmaf(p, s, -0.11643287f);
    p = fmaf(p, s,  0.19354346f);
    p = fmaf(p, s, -0.33262347f);
    p = fmaf(p, s,  0.99997726f);
    p = p * t;
    p = (ay > ax) ? (1.57079632679f - p) : p;
    p = (x < 0.0f) ? (3.14159265359f - p) : p;
    p = (y < 0.0f) ? -p : p;
    return p;
}

// ===========================================================================
// Shared device code: precompute phase for one interval v (called by block v).
// R7's EXACT serial coefficient summation order (absmax 0.03125 verified; R8's
// prefix-scan order tripled absmax to 0.09375 for zero speed gain -> reverted).
// W1/b1/W2/W3 read straight from global: per-j W1/b1 are wave-uniform s_loads;
// W2[j*64+i] and W3[j*48+o] are lane-consecutive -> coalesced. No big staging.
// ===========================================================================
__device__ __forceinline__ void precompute_interval(
    int v, int tid,
    const float* __restrict__ theta_w, const float* __restrict__ theta_h,
    const float* __restrict__ theta_d,
    const float* __restrict__ W1, const float* __restrict__ b1,
    const float* __restrict__ W2, const float* __restrict__ b2,
    const float* __restrict__ W3, const float* __restrict__ b3,
    float* __restrict__ ws,
    float* p_tjs, float* p_sAv, float* p_sBv, float* p_sknotS, float* p_rroot,
    int* p_srnk, int* p_jinv)
{
    if (tid < 64) {
        const float w1 = W1[tid], bb = b1[tid];
        p_tjs[tid] = (w1 != 0.0f) ? (-bb / w1) : INFINITY;
    }
    __syncthreads();
    if (tid < 64) {                       // distinct ranks, tie-break by index
        const float t = p_tjs[tid];
        int rk = 0;
        #pragma unroll 8
        for (int k2 = 0; k2 < 64; k2++) {
            const float tk = p_tjs[k2];
            rk += (tk < t || (tk == t && k2 < tid)) ? 1 : 0;
        }
        p_srnk[tid] = rk;
        p_sknotS[rk] = t;
    }
    __syncthreads();

    // A,B for interval v (harness-verified math, R5..R8)
    if (tid < 64) {
        const int i = tid;
        float cA = 0.0f, cB = b2[i];
        #pragma unroll 8
        for (int j = 0; j < 64; j++) {
            const float w1 = W1[j];            // uniform -> s_load
            const float bb = b1[j];
            const float w2 = W2[j * 64 + i];   // coalesced
            if (w1 > 0.0f) {
                if (p_srnk[j] < v)  { cA = fmaf(w1, w2, cA); cB = fmaf(bb, w2, cB); }
            } else if (w1 < 0.0f) {
                if (p_srnk[j] >= v) { cA = fmaf(w1, w2, cA); cB = fmaf(bb, w2, cB); }
            } else {
                cB = fmaf(fmaxf(bb, 0.0f), w2, cB);
            }
        }
        p_sAv[i] = cA; p_sBv[i] = cB;
    }
    __syncthreads();

    // sub-roots, ranks, inverse permutation, sorted write
    if (tid < 64)
        p_rroot[tid] = (p_sAv[tid] != 0.0f) ? (-p_sBv[tid] / p_sAv[tid]) : INFINITY;
    __syncthreads();
    if (tid < 64) {
        const float t = p_rroot[tid];
        int rk = 0;
        #pragma unroll 8
        for (int k2 = 0; k2 < 64; k2++) {
            const float tk = p_rroot[k2];
            rk += (tk < t || (tk == t && k2 < tid)) ? 1 : 0;
        }
        p_jinv[rk] = tid;
        ws[WS_SROOT + v * 64 + rk] = t;
    }
    __syncthreads();

    // coefficient rows: R7 serial incremental order. lane = o; W3 coalesced.
    if (tid < 48) {
        const int o = tid;
        float a = 0.0f, b = b3[o];
        #pragma unroll 8
        for (int j = 0; j < 64; j++) {
            const float A = p_sAv[j], B = p_sBv[j];
            const float w3 = W3[j * 48 + o];
            const bool act = (A < 0.0f) || (A == 0.0f && B > 0.0f);
            const float m = act ? w3 : 0.0f;
            a = fmaf(A, m, a);
            b = fmaf(B, m, b);
        }
        float* __restrict__ rowbase = ws + WS_COEF + (size_t)(v * 65) * 96;
        rowbase[2 * o]     = a;
        rowbase[2 * o + 1] = b;
        #pragma unroll 4
        for (int s = 1; s <= 64; s++) {
            const int js = p_jinv[s - 1];
            const float A = p_sAv[js], B = p_sBv[js];
            const float w3 = W3[js * 48 + o];
            const float sgn = (A > 0.0f) ? w3 : ((A < 0.0f) ? -w3 : 0.0f);
            a = fmaf(A, sgn, a);
            b = fmaf(B, sgn, b);
            rowbase[s * 96 + 2 * o]     = a;
            rowbase[s * 96 + 2 * o + 1] = b;
        }
    }

    // block 0 only: spline tables + sorted outer knots
    if (v == 0 && tid < 64) {
        ws[WS_KNOT + tid] = p_sknotS[tid];

        float vw = theta_w[tid];
        float vh = theta_h[tid];
        float mw = vw, mh = vh;
        #pragma unroll
        for (int off = 32; off > 0; off >>= 1) {
            mw = fmaxf(mw, __shfl_xor(mw, off));
            mh = fmaxf(mh, __shfl_xor(mh, off));
        }
        const float ew = expf(vw - mw);
        const float eh = expf(vh - mh);
        float sumw = ew, sumh = eh;
        #pragma unroll
        for (int off = 32; off > 0; off >>= 1) {
            sumw += __shfl_xor(sumw, off);
            sumh += __shfl_xor(sumh, off);
        }
        float cw = ew / sumw * 2.0f;
        float ch = eh / sumh * 2.0f;
        #pragma unroll
        for (int off = 1; off < 64; off <<= 1) {   // inclusive shfl scan
            const float uw = __shfl_up(cw, off);
            const float uh = __shfl_up(ch, off);
            if (tid >= off) { cw += uw; ch += uh; }
        }
        ws[WS_SXK + 1 + tid] = cw - 1.0f;
        ws[WS_SYK + 1 + tid] = ch - 1.0f;
        if (tid < KS - 1) {
            const float x = theta_d[tid];
            const float sp = (x > 20.0f) ? x : log1pf(expf(x));
            ws[WS_SDK + 1 + tid] = sp + 0.001f;
        }
        if (tid == 0) {
            ws[WS_SXK] = -1.0f;
            ws[WS_SYK] = -1.0f;
            ws[WS_SDK] = 1.0f;
            ws[WS_SDK + KS] = 1.0f;
        }
    }
}

// Shared device code: R6-verified per-point main body (59.5 us path).
__device__ __forceinline__ void main_point(
    int idx, int n, float rv, float zz,
    const float* sxk, const float* syk, const float* sdk,
    const float* sknot, const float* sroots,
    const float* __restrict__ ws, float* __restrict__ out)
{
    // ---------------- spline ----------------
    int lo = 0, hi = KS + 1;
    while (lo < hi) {
        const int mid = (lo + hi) >> 1;
        if (sxk[mid] < rv) lo = mid + 1; else hi = mid;
    }
    int k = lo;
    k = (k == 0) ? 1 : k;
    k = (k == KS + 1) ? KS : k;
    k -= 1;
    const float x_k = sxk[k], x_nk = sxk[k + 1];
    const float y_k = syk[k], y_nk = syk[k + 1];
    const float d_k = sdk[k], d_nk = sdk[k + 1];
    const float rdx = frcp(x_nk - x_k);
    const float dy  = y_nk - y_k;
    const float s_k = dy * rdx;
    const float eps = (rv - x_k) * rdx;
    const float ome = 1.0f - eps;
    const float den = s_k + (d_nk + d_k - 2.0f * s_k) * eps * ome;
    const float rden = frcp(den);
    const float tr  = fmaf(dy * (s_k * eps * eps + d_k * eps * ome), rden, y_k);
    const float dtr = s_k * s_k * (d_nk * eps * eps + 2.0f * s_k * eps * ome + d_k * ome * ome)
                      * rden * rden;

    // ---------------- region lookup: outer interval v, sub-region s ----------
    int lo2 = 0, hi2 = KS;
    while (lo2 < hi2) {
        const int mid = (lo2 + hi2) >> 1;
        if (sknot[mid] < rv) lo2 = mid + 1; else hi2 = mid;
    }
    const int v = lo2;                    // 0..64
    const int rbase = v * 65;
    int lo3 = 0, hi3 = 64;
    while (lo3 < hi3) {
        const int mid = (lo3 + hi3) >> 1;
        if (sroots[rbase + mid] < rv) lo3 = mid + 1; else hi3 = mid;
    }
    const int s = lo3;                    // 0..64

    const float4* __restrict__ row4 =
        (const float4*)(ws + WS_COEF + (size_t)(v * 65 + s) * 96);

    // ---------------- theta logits: th_q = a*rv + b ----------------
    float th[16];
    #pragma unroll
    for (int o8 = 0; o8 < 8; o8++) {
        const float4 c = row4[o8];
        th[2 * o8]     = fmaf(c.x, rv, c.y);
        th[2 * o8 + 1] = fmaf(c.z, rv, c.w);
    }
    float mx = th[0];
    #pragma unroll
    for (int q = 1; q < 16; q++) mx = fmaxf(mx, th[q]);

    float cz, sz;
    __sincosf(zz, &sz, &cz);

    float wsum = 0.0f, tsum = 0.0f, dsum = 0.0f;

    #pragma unroll 4
    for (int q = 0; q < 16; q++) {
        const float4 c = row4[8 + q];     // (a_wx, b_wx, a_wy, b_wy)
        const float rwx = fmaf(c.x, rv, c.y);
        const float rwy = fmaf(c.z, rv, c.w);
        const float nrm = __builtin_amdgcn_sqrtf(rwx * rwx + rwy * rwy);
        const float scl = 0.99f * frcp(1.0f + nrm);
        const float wxx = scl * rwx, wyy = scl * rwy;
        const float wn2 = wxx * wxx + wyy * wyy;
        const float omw = 1.0f - wn2;
        const float dzx = cz - wxx, dzy = sz - wyy;
        const float dn2z = dzx * dzx + dzy * dzy;
        const float cf = omw * frcp(dn2z);
        const float hzx = cf * dzx - wxx;
        const float hzy = cf * dzy - wyy;
        const float d0x = 1.0f - wxx, d0y = -wyy;
        const float dn20 = d0x * d0x + d0y * d0y;
        const float c0 = omw * frcp(dn20);
        const float h0x = c0 * d0x - wxx;
        const float h0y = c0 * d0y - wyy;
        const float cross = hzy * h0x - hzx * h0y;
        const float dotp  = hzx * h0x + hzy * h0y;
        float tx = fast_atan2(cross, dotp);
        tx = (tx >= 0.0f) ? tx : tx + TWO_PI_F;

        const float ew = __expf(th[q] - mx);
        wsum += ew;
        tsum += ew * tx;
        dsum += ew * cf;                  // |dh| = cf exactly
    }

    const float inv = frcp(wsum);
    const float tz  = tsum * inv;
    const float dtz = dsum * inv;
    const float ldj = __logf(dtr) + __logf(dtz);

    out[idx]         = tr;
    out[n + idx]     = tz;
    out[2 * n + idx] = ldj;
}

// ===========================================================================
// COOPERATIVE FUSED KERNEL: phase 1 (blocks 0..64 precompute) -> grid sync ->
// phase 2 (all blocks grid-stride the main body). Eliminates the second
// dispatch whose launch/drain overhead measured ~49 us (R7/R8 gap analysis:
// kernel-work changes in precompute moved the bench 0 us).
// __threadfence() on both sides of grid.sync(): cross-XCD L2 visibility that
// the two-kernel version got implicitly from kernel-boundary cache ops.
// ===========================================================================
__global__ __launch_bounds__(256)
void fused_kernel(const float* __restrict__ r_in,
                  const float* __restrict__ z_in,
                  const float* __restrict__ theta_w,
                  const float* __restrict__ theta_h,
                  const float* __restrict__ theta_d,
                  const float* __restrict__ W1,
                  const float* __restrict__ b1,
                  const float* __restrict__ W2,
                  const float* __restrict__ b2,
                  const float* __restrict__ W3,
                  const float* __restrict__ b3,
                  float* __restrict__ ws,
                  float* __restrict__ out,
                  int n, int ntiles)
{
    __shared__ float sxk[KS + 1], syk[KS + 1], sdk[KS + 1];
    __shared__ float sknot[KS];
    __shared__ float sroots[65 * 65];    // stride 65 (odd) -> banks spread
    __shared__ float p_tjs[64], p_sAv[64], p_sBv[64], p_sknotS[64], p_rroot[64];
    __shared__ int   p_srnk[64], p_jinv[64];

    const int tid = threadIdx.x;

    // -------- phase 1 --------
    if (blockIdx.x < 65) {
        precompute_interval(blockIdx.x, tid,
                            theta_w, theta_h, theta_d, W1, b1, W2, b2, W3, b3,
                            ws, p_tjs, p_sAv, p_sBv, p_sknotS, p_rroot,
                            p_srnk, p_jinv);
    }
    __threadfence();
    cg::this_grid().sync();
    __threadfence();

    // -------- phase 2: stage tables, then grid-stride tiles --------
    for (int t2 = tid; t2 < 65; t2 += 256) {
        sxk[t2] = ws[WS_SXK + t2];
        syk[t2] = ws[WS_SYK + t2];
        sdk[t2] = ws[WS_SDK + t2];
    }
    for (int t2 = tid; t2 < 64; t2 += 256) sknot[t2] = ws[WS_KNOT + t2];
    for (int t2 = tid; t2 < 65 * 64; t2 += 256) {
        const int v2 = t2 >> 6, m = t2 & 63;
        sroots[v2 * 65 + m] = ws[WS_SROOT + t2];
    }
    __syncthreads();

    for (int tile = blockIdx.x; tile < ntiles; tile += gridDim.x) {
        const int idx = tile * 256 + tid;
        if (idx >= n) continue;
        main_point(idx, n, r_in[idx], z_in[idx],
                   sxk, syk, sdk, sknot, sroots, ws, out);
    }
}

// ===========================================================================
// FALLBACK two-kernel path (if cooperative launch is rejected): standalone
// precompute (65 blocks) + R6-verified main kernel. Same device code.
// ===========================================================================
__global__ __launch_bounds__(256)
void precompute_k(const float* __restrict__ theta_w,
                  const float* __restrict__ theta_h,
                  const float* __restrict__ theta_d,
                  const float* __restrict__ W1,
                  const float* __restrict__ b1,
                  const float* __restrict__ W2,
                  const float* __restrict__ b2,
                  const float* __restrict__ W3,
                  const float* __restrict__ b3,
                  float* __restrict__ ws)
{
    __shared__ float p_tjs[64], p_sAv[64], p_sBv[64], p_sknotS[64], p_rroot[64];
    __shared__ int   p_srnk[64], p_jinv[64];
    precompute_interval(blockIdx.x, threadIdx.x,
                        theta_w, theta_h, theta_d, W1, b1, W2, b2, W3, b3,
                        ws, p_tjs, p_sAv, p_sBv, p_sknotS, p_rroot,
                        p_srnk, p_jinv);
}

__global__ __launch_bounds__(256)
void mobius_spline_kernel(const float* __restrict__ r_in,
                          const float* __restrict__ z_in,
                          const float* __restrict__ ws,
                          float* __restrict__ out,
                          int n)
{
    __shared__ float sxk[KS + 1], syk[KS + 1], sdk[KS + 1];
    __shared__ float sknot[KS];
    __shared__ float sroots[65 * 65];

    const int tid = threadIdx.x;

    for (int t2 = tid; t2 < 65; t2 += 256) {
        sxk[t2] = ws[WS_SXK + t2];
        syk[t2] = ws[WS_SYK + t2];
        sdk[t2] = ws[WS_SDK + t2];
    }
    for (int t2 = tid; t2 < 64; t2 += 256) sknot[t2] = ws[WS_KNOT + t2];
    for (int t2 = tid; t2 < 65 * 64; t2 += 256) {
        const int v2 = t2 >> 6, m = t2 & 63;
        sroots[v2 * 65 + m] = ws[WS_SROOT + t2];
    }
    __syncthreads();

    const int idx = blockIdx.x * 256 + tid;
    if (idx >= n) return;
    main_point(idx, n, r_in[idx], z_in[idx],
               sxk, syk, sdk, sknot, sroots, ws, out);
}

extern "C" void kernel_launch(void* const* d_in, const int* in_sizes, int n_in,
                              void* d_out, int out_size, void* d_ws, size_t ws_size,
                              hipStream_t stream) {
    const int n = in_sizes[0];  // 1,000,000
    float* ws = (float*)d_ws;
    const int ntiles = (n + 255) / 256;

    const float* r_in = (const float*)d_in[0];
    const float* z_in = (const float*)d_in[1];
    const float* tw   = (const float*)d_in[2];
    const float* thh  = (const float*)d_in[3];
    const float* td   = (const float*)d_in[4];
    const float* W1   = (const float*)d_in[5];
    const float* b1   = (const float*)d_in[6];
    const float* W2   = (const float*)d_in[7];
    const float* b2   = (const float*)d_in[8];
    const float* W3   = (const float*)d_in[9];
    const float* b3   = (const float*)d_in[10];
    float* out = (float*)d_out;

    if (ws_size >= (size_t)WS_NEED * sizeof(float)) {
        // ---- try the cooperative fused path ----
        static int s_maxGrid = -1;
        if (s_maxGrid < 0) {
            int nb = 0, dev = 0, cus = 0;
            if (hipOccupancyMaxActiveBlocksPerMultiprocessor(&nb, fused_kernel, 256, 0)
                    == hipSuccess &&
                hipGetDevice(&dev) == hipSuccess &&
                hipDeviceGetAttribute(&cus, hipDeviceAttributeMultiprocessorCount, dev)
                    == hipSuccess && nb > 0 && cus > 0) {
                s_maxGrid = nb * cus;
            } else {
                s_maxGrid = 0;   // queries failed -> never try cooperative
            }
        }
        int grid = (ntiles < s_maxGrid) ? ntiles : s_maxGrid;
        if (grid >= 65) {
            int n_arg = n, nt_arg = ntiles;
            void* args[] = { (void*)&r_in, (void*)&z_in, (void*)&tw, (void*)&thh,
                             (void*)&td, (void*)&W1, (void*)&b1, (void*)&W2,
                             (void*)&b2, (void*)&W3, (void*)&b3, (void*)&ws,
                             (void*)&out, (void*)&n_arg, (void*)&nt_arg };
            hipError_t e = hipLaunchCooperativeKernel((const void*)fused_kernel,
                                                      dim3(grid), dim3(256),
                                                      args, 0, stream);
            if (e == hipSuccess) return;
            (void)hipGetLastError();   // clear; fall through to two-kernel path
        }

        // ---- fallback: two-kernel path (R7-order precompute + R6 main) ----
        hipLaunchKernelGGL(precompute_k, dim3(65), dim3(256), 0, stream,
                           tw, thh, td, W1, b1, W2, b2, W3, b3, ws);
        hipLaunchKernelGGL(mobius_spline_kernel, dim3(ntiles), dim3(256), 0, stream,
                           r_in, z_in, ws, out, n);
    } else {
        // ws too small for coef table: never observed on this harness (fast
        // path ran every round since R6); emit the two-kernel path anyway.
        hipLaunchKernelGGL(precompute_k, dim3(65), dim3(256), 0, stream,
                           tw, thh, td, W1, b1, W2, b2, W3, b3, ws);
        hipLaunchKernelGGL(mobius_spline_kernel, dim3(ntiles), dim3(256), 0, stream,
                           r_in, z_in, ws, out, n);
    }
}

// Round 11
// 157.764 us; speedup vs baseline: 2.2569x; 2.2569x over previous
//
#include <hip/hip_runtime.h>
#include <math.h>

#define KM 16
#define KS 64
#define TWO_PI_F 6.283185307179586477f

// Workspace float-offset layout:
//   [0..64]      sxk (65)   [65..129] syk   [130..194] sdk
//   [195..258]   sknot (64) sorted outer knots
//   [8709..12868]   SROOT: 65 intervals * 64 sorted sub-roots
//   [12872..418471] COEF: 4225 regions * 96 floats (48 (a,b) pairs)
#define WS_SXK   0
#define WS_SYK   65
#define WS_SDK   130
#define WS_KNOT  195
#define WS_SROOT 8709
#define WS_COEF  12872
#define WS_NEED  (12872 + 4225 * 96)

__device__ __forceinline__ float frcp(float x) { return __builtin_amdgcn_rcpf(x); }

// 4-quadrant atan2, max err ~1e-5 rad (tolerance 3.1e-2).
__device__ __forceinline__ float fast_atan2(float y, float x) {
    const float ax = fabsf(x), ay = fabsf(y);
    const float mx = fmaxf(ax, ay), mn = fminf(ax, ay);
    const float t = mn * frcp(mx);
    const float s = t * t;
    float p = -0.01172120f;
    p = fmaf(p, s,  0.05265332f);
    p = fmaf(p, s, -0.11643287f);
    p = fmaf(p, s,  0.19354346f);
    p = fmaf(p, s, -0.33262347f);
    p = fmaf(p, s,  0.99997726f);
    p = p * t;
    p = (ay > ax) ? (1.57079632679f - p) : p;
    p = (x < 0.0f) ? (3.14159265359f - p) : p;
    p = (y < 0.0f) ? -p : p;
    return p;
}

// ===========================================================================
// Precompute for one interval v — VERBATIM the R9-verified device function
// (ran on hardware, passed, absmax 0.03125). R7 serial coefficient order.
// ===========================================================================
__device__ __forceinline__ void precompute_interval(
    int v, int tid,
    const float* __restrict__ theta_w, const float* __restrict__ theta_h,
    const float* __restrict__ theta_d,
    const float* __restrict__ W1, const float* __restrict__ b1,
    const float* __restrict__ W2, const float* __restrict__ b2,
    const float* __restrict__ W3, const float* __restrict__ b3,
    float* __restrict__ ws,
    float* p_tjs, float* p_sAv, float* p_sBv, float* p_sknotS, float* p_rroot,
    int* p_srnk, int* p_jinv)
{
    if (tid < 64) {
        const float w1 = W1[tid], bb = b1[tid];
        p_tjs[tid] = (w1 != 0.0f) ? (-bb / w1) : INFINITY;
    }
    __syncthreads();
    if (tid < 64) {                       // distinct ranks, tie-break by index
        const float t = p_tjs[tid];
        int rk = 0;
        #pragma unroll 8
        for (int k2 = 0; k2 < 64; k2++) {
            const float tk = p_tjs[k2];
            rk += (tk < t || (tk == t && k2 < tid)) ? 1 : 0;
        }
        p_srnk[tid] = rk;
        p_sknotS[rk] = t;
    }
    __syncthreads();

    if (tid < 64) {                       // A,B for interval v
        const int i = tid;
        float cA = 0.0f, cB = b2[i];
        #pragma unroll 8
        for (int j = 0; j < 64; j++) {
            const float w1 = W1[j];            // uniform -> s_load
            const float bb = b1[j];
            const float w2 = W2[j * 64 + i];   // coalesced
            if (w1 > 0.0f) {
                if (p_srnk[j] < v)  { cA = fmaf(w1, w2, cA); cB = fmaf(bb, w2, cB); }
            } else if (w1 < 0.0f) {
                if (p_srnk[j] >= v) { cA = fmaf(w1, w2, cA); cB = fmaf(bb, w2, cB); }
            } else {
                cB = fmaf(fmaxf(bb, 0.0f), w2, cB);
            }
        }
        p_sAv[i] = cA; p_sBv[i] = cB;
    }
    __syncthreads();

    if (tid < 64)
        p_rroot[tid] = (p_sAv[tid] != 0.0f) ? (-p_sBv[tid] / p_sAv[tid]) : INFINITY;
    __syncthreads();
    if (tid < 64) {
        const float t = p_rroot[tid];
        int rk = 0;
        #pragma unroll 8
        for (int k2 = 0; k2 < 64; k2++) {
            const float tk = p_rroot[k2];
            rk += (tk < t || (tk == t && k2 < tid)) ? 1 : 0;
        }
        p_jinv[rk] = tid;
        ws[WS_SROOT + v * 64 + rk] = t;
    }
    __syncthreads();

    // coefficient rows: R7 serial incremental order. lane = o; W3 coalesced.
    if (tid < 48) {
        const int o = tid;
        float a = 0.0f, b = b3[o];
        #pragma unroll 8
        for (int j = 0; j < 64; j++) {
            const float A = p_sAv[j], B = p_sBv[j];
            const float w3 = W3[j * 48 + o];
            const bool act = (A < 0.0f) || (A == 0.0f && B > 0.0f);
            const float m = act ? w3 : 0.0f;
            a = fmaf(A, m, a);
            b = fmaf(B, m, b);
        }
        float* __restrict__ rowbase = ws + WS_COEF + (size_t)(v * 65) * 96;
        rowbase[2 * o]     = a;
        rowbase[2 * o + 1] = b;
        #pragma unroll 4
        for (int s = 1; s <= 64; s++) {
            const int js = p_jinv[s - 1];
            const float A = p_sAv[js], B = p_sBv[js];
            const float w3 = W3[js * 48 + o];
            const float sgn = (A > 0.0f) ? w3 : ((A < 0.0f) ? -w3 : 0.0f);
            a = fmaf(A, sgn, a);
            b = fmaf(B, sgn, b);
            rowbase[s * 96 + 2 * o]     = a;
            rowbase[s * 96 + 2 * o + 1] = b;
        }
    }

    if (v == 0 && tid < 64) {             // spline tables + sorted outer knots
        ws[WS_KNOT + tid] = p_sknotS[tid];

        float vw = theta_w[tid];
        float vh = theta_h[tid];
        float mw = vw, mh = vh;
        #pragma unroll
        for (int off = 32; off > 0; off >>= 1) {
            mw = fmaxf(mw, __shfl_xor(mw, off));
            mh = fmaxf(mh, __shfl_xor(mh, off));
        }
        const float ew = expf(vw - mw);
        const float eh = expf(vh - mh);
        float sumw = ew, sumh = eh;
        #pragma unroll
        for (int off = 32; off > 0; off >>= 1) {
            sumw += __shfl_xor(sumw, off);
            sumh += __shfl_xor(sumh, off);
        }
        float cw = ew / sumw * 2.0f;
        float ch = eh / sumh * 2.0f;
        #pragma unroll
        for (int off = 1; off < 64; off <<= 1) {   // inclusive shfl scan
            const float uw = __shfl_up(cw, off);
            const float uh = __shfl_up(ch, off);
            if (tid >= off) { cw += uw; ch += uh; }
        }
        ws[WS_SXK + 1 + tid] = cw - 1.0f;
        ws[WS_SYK + 1 + tid] = ch - 1.0f;
        if (tid < KS - 1) {
            const float x = theta_d[tid];
            const float sp = (x > 20.0f) ? x : log1pf(expf(x));
            ws[WS_SDK + 1 + tid] = sp + 0.001f;
        }
        if (tid == 0) {
            ws[WS_SXK] = -1.0f;
            ws[WS_SYK] = -1.0f;
            ws[WS_SDK] = 1.0f;
            ws[WS_SDK + KS] = 1.0f;
        }
    }
}

__global__ __launch_bounds__(256)
void precompute_k(const float* __restrict__ theta_w,
                  const float* __restrict__ theta_h,
                  const float* __restrict__ theta_d,
                  const float* __restrict__ W1,
                  const float* __restrict__ b1,
                  const float* __restrict__ W2,
                  const float* __restrict__ b2,
                  const float* __restrict__ W3,
                  const float* __restrict__ b3,
                  float* __restrict__ ws)
{
    __shared__ float p_tjs[64], p_sAv[64], p_sBv[64], p_sknotS[64], p_rroot[64];
    __shared__ int   p_srnk[64], p_jinv[64];
    precompute_interval(blockIdx.x, threadIdx.x,
                        theta_w, theta_h, theta_d, W1, b1, W2, b2, W3, b3,
                        ws, p_tjs, p_sAv, p_sBv, p_sknotS, p_rroot,
                        p_srnk, p_jinv);
}

// ===========================================================================
// MAIN kernel: 2 points per thread (idx, idx+256 — both coalesced).
// The 19 serially-dependent LDS search steps per point are the latency
// bottleneck (VALUBusy 60% at VGPR=32 -> huge register headroom). The three
// binary searches become fixed-trip branchless loops, manually interleaved
// across the two points: each step issues 2-4 INDEPENDENT LDS reads instead
// of 1 -> exposed latency per point halves. Gathers for both points issue
// together (2x MLP). Arithmetic per point is IDENTICAL to the R9-verified
// main_point (absmax 0.03125) — only instruction interleaving changes.
// ===========================================================================
__global__ __launch_bounds__(256)
void mobius_spline_kernel2(const float* __restrict__ r_in,
                           const float* __restrict__ z_in,
                           const float* __restrict__ ws,
                           float* __restrict__ out,
                           int n)
{
    __shared__ float sxk[KS + 1], syk[KS + 1], sdk[KS + 1];
    __shared__ float sknot[KS];
    __shared__ float sroots[65 * 65];    // stride 65 (odd) -> banks spread

    const int tid = threadIdx.x;

    for (int t2 = tid; t2 < 65; t2 += 256) {
        sxk[t2] = ws[WS_SXK + t2];
        syk[t2] = ws[WS_SYK + t2];
        sdk[t2] = ws[WS_SDK + t2];
    }
    for (int t2 = tid; t2 < 64; t2 += 256) sknot[t2] = ws[WS_KNOT + t2];
    for (int t2 = tid; t2 < 65 * 64; t2 += 256) {
        const int v2 = t2 >> 6, m = t2 & 63;
        sroots[v2 * 65 + m] = ws[WS_SROOT + t2];
    }
    __syncthreads();

    const int i0 = blockIdx.x * 512 + tid;
    const int i1 = i0 + 256;
    if (i0 >= n) return;
    const bool ok1 = (i1 < n);

    const float rv0 = r_in[i0];
    const float zz0 = z_in[i0];
    const float rv1 = ok1 ? r_in[i1] : rv0;   // dummy duplicate for the tail
    const float zz1 = ok1 ? z_in[i1] : zz0;

    // sincos early: transcendental latency overlaps the searches below
    float cz0, sz0, cz1, sz1;
    __sincosf(zz0, &sz0, &cz0);
    __sincosf(zz1, &sz1, &cz1);

    // ---- interleaved fixed-trip searches: spline knot (range 65, 7 steps)
    //      and outer interval (range 64, 6 steps), 2 points each ----
    int alo0 = 0, ahi0 = KS + 1, alo1 = 0, ahi1 = KS + 1;   // sxk
    int blo0 = 0, bhi0 = KS,     blo1 = 0, bhi1 = KS;       // sknot
    #pragma unroll
    for (int it = 0; it < 7; ++it) {
        const int am0 = (alo0 + ahi0) >> 1, am1 = (alo1 + ahi1) >> 1;
        const bool ag0 = alo0 < ahi0, ag1 = alo1 < ahi1;
        const bool ac0 = sxk[am0] < rv0, ac1 = sxk[am1] < rv1;
        alo0 = (ag0 && ac0) ? am0 + 1 : alo0;  ahi0 = (ag0 && !ac0) ? am0 : ahi0;
        alo1 = (ag1 && ac1) ? am1 + 1 : alo1;  ahi1 = (ag1 && !ac1) ? am1 : ahi1;
        if (it < 6) {
            const int bm0 = (blo0 + bhi0) >> 1, bm1 = (blo1 + bhi1) >> 1;
            const bool bg0 = blo0 < bhi0, bg1 = blo1 < bhi1;
            const bool bc0 = sknot[bm0] < rv0, bc1 = sknot[bm1] < rv1;
            blo0 = (bg0 && bc0) ? bm0 + 1 : blo0;  bhi0 = (bg0 && !bc0) ? bm0 : bhi0;
            blo1 = (bg1 && bc1) ? bm1 + 1 : blo1;  bhi1 = (bg1 && !bc1) ? bm1 : bhi1;
        }
    }

    // ---- spline evaluation (both points; identical arithmetic to R9) ----
    int k0 = alo0, k1 = alo1;
    k0 = (k0 == 0) ? 1 : k0;  k0 = (k0 == KS + 1) ? KS : k0;  k0 -= 1;
    k1 = (k1 == 0) ? 1 : k1;  k1 = (k1 == KS + 1) ? KS : k1;  k1 -= 1;

    const float x_k0 = sxk[k0], x_nk0 = sxk[k0 + 1];
    const float y_k0 = syk[k0], y_nk0 = syk[k0 + 1];
    const float d_k0 = sdk[k0], d_nk0 = sdk[k0 + 1];
    const float x_k1 = sxk[k1], x_nk1 = sxk[k1 + 1];
    const float y_k1 = syk[k1], y_nk1 = syk[k1 + 1];
    const float d_k1 = sdk[k1], d_nk1 = sdk[k1 + 1];

    const float rdx0 = frcp(x_nk0 - x_k0);
    const float rdx1 = frcp(x_nk1 - x_k1);
    const float dy0  = y_nk0 - y_k0, dy1 = y_nk1 - y_k1;
    const float s_k0 = dy0 * rdx0,   s_k1 = dy1 * rdx1;
    const float eps0 = (rv0 - x_k0) * rdx0, eps1 = (rv1 - x_k1) * rdx1;
    const float ome0 = 1.0f - eps0,  ome1 = 1.0f - eps1;
    const float den0 = s_k0 + (d_nk0 + d_k0 - 2.0f * s_k0) * eps0 * ome0;
    const float den1 = s_k1 + (d_nk1 + d_k1 - 2.0f * s_k1) * eps1 * ome1;
    const float rden0 = frcp(den0), rden1 = frcp(den1);
    const float tr0 = fmaf(dy0 * (s_k0 * eps0 * eps0 + d_k0 * eps0 * ome0), rden0, y_k0);
    const float tr1 = fmaf(dy1 * (s_k1 * eps1 * eps1 + d_k1 * eps1 * ome1), rden1, y_k1);
    const float dtr0 = s_k0 * s_k0 *
        (d_nk0 * eps0 * eps0 + 2.0f * s_k0 * eps0 * ome0 + d_k0 * ome0 * ome0) * rden0 * rden0;
    const float dtr1 = s_k1 * s_k1 *
        (d_nk1 * eps1 * eps1 + 2.0f * s_k1 * eps1 * ome1 + d_k1 * ome1 * ome1) * rden1 * rden1;

    // ---- sub-region search (range 64, 6 steps, depends on v) ----
    const int rb0 = blo0 * 65, rb1 = blo1 * 65;
    int clo0 = 0, chi0 = 64, clo1 = 0, chi1 = 64;
    #pragma unroll
    for (int it = 0; it < 6; ++it) {
        const int cm0 = (clo0 + chi0) >> 1, cm1 = (clo1 + chi1) >> 1;
        const bool cg0 = clo0 < chi0, cg1 = clo1 < chi1;
        const bool cc0 = sroots[rb0 + cm0] < rv0, cc1 = sroots[rb1 + cm1] < rv1;
        clo0 = (cg0 && cc0) ? cm0 + 1 : clo0;  chi0 = (cg0 && !cc0) ? cm0 : chi0;
        clo1 = (cg1 && cc1) ? cm1 + 1 : clo1;  chi1 = (cg1 && !cc1) ? cm1 : chi1;
    }

    const float4* __restrict__ row0 =
        (const float4*)(ws + WS_COEF + (size_t)(blo0 * 65 + clo0) * 96);
    const float4* __restrict__ row1 =
        (const float4*)(ws + WS_COEF + (size_t)(blo1 * 65 + clo1) * 96);

    // ---- theta logits for both points (16 gathers in flight) ----
    float th0[16], th1[16];
    #pragma unroll
    for (int o8 = 0; o8 < 8; o8++) {
        const float4 c0 = row0[o8];
        const float4 c1 = row1[o8];
        th0[2 * o8]     = fmaf(c0.x, rv0, c0.y);
        th0[2 * o8 + 1] = fmaf(c0.z, rv0, c0.w);
        th1[2 * o8]     = fmaf(c1.x, rv1, c1.y);
        th1[2 * o8 + 1] = fmaf(c1.z, rv1, c1.w);
    }
    float mx0 = th0[0], mx1 = th1[0];
    #pragma unroll
    for (int q = 1; q < 16; q++) { mx0 = fmaxf(mx0, th0[q]); mx1 = fmaxf(mx1, th1[q]); }

    float wsum0 = 0.0f, tsum0 = 0.0f, dsum0 = 0.0f;
    float wsum1 = 0.0f, tsum1 = 0.0f, dsum1 = 0.0f;

    #pragma unroll 2
    for (int q = 0; q < 16; q++) {
        const float4 c0 = row0[8 + q];
        const float4 c1 = row1[8 + q];
        // ---- point 0 ----
        {
            const float rwx = fmaf(c0.x, rv0, c0.y);
            const float rwy = fmaf(c0.z, rv0, c0.w);
            const float nrm = __builtin_amdgcn_sqrtf(rwx * rwx + rwy * rwy);
            const float scl = 0.99f * frcp(1.0f + nrm);
            const float wxx = scl * rwx, wyy = scl * rwy;
            const float wn2 = wxx * wxx + wyy * wyy;
            const float omw = 1.0f - wn2;
            const float dzx = cz0 - wxx, dzy = sz0 - wyy;
            const float dn2z = dzx * dzx + dzy * dzy;
            const float cf = omw * frcp(dn2z);
            const float hzx = cf * dzx - wxx;
            const float hzy = cf * dzy - wyy;
            const float d0x = 1.0f - wxx, d0y = -wyy;
            const float dn20 = d0x * d0x + d0y * d0y;
            const float c0f = omw * frcp(dn20);
            const float h0x = c0f * d0x - wxx;
            const float h0y = c0f * d0y - wyy;
            const float cross = hzy * h0x - hzx * h0y;
            const float dotp  = hzx * h0x + hzy * h0y;
            float tx = fast_atan2(cross, dotp);
            tx = (tx >= 0.0f) ? tx : tx + TWO_PI_F;
            const float ew = __expf(th0[q] - mx0);
            wsum0 += ew;
            tsum0 += ew * tx;
            dsum0 += ew * cf;             // |dh| = cf exactly
        }
        // ---- point 1 ----
        {
            const float rwx = fmaf(c1.x, rv1, c1.y);
            const float rwy = fmaf(c1.z, rv1, c1.w);
            const float nrm = __builtin_amdgcn_sqrtf(rwx * rwx + rwy * rwy);
            const float scl = 0.99f * frcp(1.0f + nrm);
            const float wxx = scl * rwx, wyy = scl * rwy;
            const float wn2 = wxx * wxx + wyy * wyy;
            const float omw = 1.0f - wn2;
            const float dzx = cz1 - wxx, dzy = sz1 - wyy;
            const float dn2z = dzx * dzx + dzy * dzy;
            const float cf = omw * frcp(dn2z);
            const float hzx = cf * dzx - wxx;
            const float hzy = cf * dzy - wyy;
            const float d0x = 1.0f - wxx, d0y = -wyy;
            const float dn20 = d0x * d0x + d0y * d0y;
            const float c0f = omw * frcp(dn20);
            const float h0x = c0f * d0x - wxx;
            const float h0y = c0f * d0y - wyy;
            const float cross = hzy * h0x - hzx * h0y;
            const float dotp  = hzx * h0x + hzy * h0y;
            float tx = fast_atan2(cross, dotp);
            tx = (tx >= 0.0f) ? tx : tx + TWO_PI_F;
            const float ew = __expf(th1[q] - mx1);
            wsum1 += ew;
            tsum1 += ew * tx;
            dsum1 += ew * cf;
        }
    }

    {
        const float inv = frcp(wsum0);
        const float tz  = tsum0 * inv;
        const float dtz = dsum0 * inv;
        const float ldj = __logf(dtr0) + __logf(dtz);
        out[i0]         = tr0;
        out[n + i0]     = tz;
        out[2 * n + i0] = ldj;
    }
    if (ok1) {
        const float inv = frcp(wsum1);
        const float tz  = tsum1 * inv;
        const float dtz = dsum1 * inv;
        const float ldj = __logf(dtr1) + __logf(dtz);
        out[i1]         = tr1;
        out[n + i1]     = tz;
        out[2 * n + i1] = ldj;
    }
}

extern "C" void kernel_launch(void* const* d_in, const int* in_sizes, int n_in,
                              void* d_out, int out_size, void* d_ws, size_t ws_size,
                              hipStream_t stream) {
    const int n = in_sizes[0];  // 1,000,000
    float* ws = (float*)d_ws;

    hipLaunchKernelGGL(precompute_k, dim3(65), dim3(256), 0, stream,
                       (const float*)d_in[2], (const float*)d_in[3],
                       (const float*)d_in[4], (const float*)d_in[5],
                       (const float*)d_in[6], (const float*)d_in[7],
                       (const float*)d_in[8], (const float*)d_in[9],
                       (const float*)d_in[10], ws);

    const int blocks2 = (n + 511) / 512;
    hipLaunchKernelGGL(mobius_spline_kernel2, dim3(blocks2), dim3(256), 0, stream,
                       (const float*)d_in[0], (const float*)d_in[1],
                       (const float*)ws, (float*)d_out, n);
}